// Round 4
// baseline (314.758 us; speedup 1.0000x reference)
//
#include <hip/hip_runtime.h>

#define NSAMP 128
#define VD 128      // voxel grid is 128^3 (fixed by problem instance)
#define SPLIT 8     // segment threads per ray
#define SEG (NSAMP / SPLIT)

__global__ __launch_bounds__(256)
void VoxelRenderer_kernel(const float* __restrict__ vol,   // [B,128,128,128,4]
                          const float* __restrict__ pose,  // [B,4,4]
                          const float* __restrict__ Kmat,  // [B,3,3]
                          const float* __restrict__ bmin,  // [B,3]
                          const float* __restrict__ bmax,  // [B,3]
                          const int* __restrict__ dH,
                          const int* __restrict__ dW,
                          float* __restrict__ out,         // [B,3,H,W]
                          int totalThreads)                // B*H*W*SPLIT
{
    const int tid = blockIdx.x * blockDim.x + threadIdx.x;
    if (tid >= totalThreads) return;
    const int s   = tid & (SPLIT - 1);   // segment index within ray
    const int ray = tid >> 3;            // log2(SPLIT)=3
    const int H = dH[0], W = dW[0];
    const int N = H * W;
    const int b = ray / N;
    const int pix = ray - b * N;
    const int i = pix / W;
    const int j = pix - i * W;

    // ---- camera / ray setup ----
    const float* P  = pose + b * 16;
    const float* Kb = Kmat + b * 9;
    const float fx = Kb[0], cx = Kb[2], fy = Kb[4], cy = Kb[5];

    const float dcx = ((float)j - cx) / fx;
    const float dcy = -((float)i - cy) / fy;
    const float dcz = -1.0f;

    float dx = P[0]*dcx + P[1]*dcy + P[2]*dcz;
    float dy = P[4]*dcx + P[5]*dcy + P[6]*dcz;
    float dz = P[8]*dcx + P[9]*dcy + P[10]*dcz;
    float nrm = sqrtf(dx*dx + dy*dy + dz*dz);
    nrm = fmaxf(nrm, 1e-12f);
    dx /= nrm; dy /= nrm; dz /= nrm;

    const float ox = P[3], oy = P[7], oz = P[11];

    const float bx0 = bmin[b*3+0], by0 = bmin[b*3+1], bz0 = bmin[b*3+2];
    const float bx1 = bmax[b*3+0], by1 = bmax[b*3+1], bz1 = bmax[b*3+2];

    // ---- ray/box intersection (exact reference arithmetic) ----
    const float ivx = 1.0f / (dx + 1e-10f);
    const float ivy = 1.0f / (dy + 1e-10f);
    const float ivz = 1.0f / (dz + 1e-10f);

    float ta, tb;
    ta = (bx0 - ox) * ivx; tb = (bx1 - ox) * ivx;
    const float t1x = fminf(ta, tb), t2x = fmaxf(ta, tb);
    ta = (by0 - oy) * ivy; tb = (by1 - oy) * ivy;
    const float t1y = fminf(ta, tb), t2y = fmaxf(ta, tb);
    ta = (bz0 - oz) * ivz; tb = (bz1 - oz) * ivz;
    const float t1z = fminf(ta, tb), t2z = fmaxf(ta, tb);

    const float near = fmaxf(fmaxf(t1x, fmaxf(t1y, t1z)), 0.1f);
    const float far  = fmaxf(fminf(t2x, fminf(t2y, t2z)), near + 0.1f);

    // ---- voxel-space affine coords: v(t) = a + b*t  (align_corners=True) ----
    const float sxs = (bx1 - bx0) + 1e-10f;
    const float sys = (by1 - by0) + 1e-10f;
    const float szs = (bz1 - bz0) + 1e-10f;
    const float C = (float)(VD - 1);
    const float axv = (ox - bx0) / sxs * C, bxv = dx / sxs * C;
    const float ayv = (oy - by0) / sys * C, byv = dy / sys * C;
    const float azv = (oz - bz0) / szs * C, bzv = dz / szs * C;

    const float dt = (far - near) * (1.0f / (float)(NSAMP - 1));

    const float* __restrict__ V = vol + (size_t)b * VD * VD * VD * 4;

    // ---- this thread's contiguous sample segment ----
    float T = 1.0f;                       // local transmittance within segment
    float rr = 0.0f, gg = 0.0f, bb = 0.0f, aw = 0.0f;
    const int k0 = s * SEG;

    for (int kk = 0; kk < SEG; ++kk) {
        const int k = k0 + kk;
        const float t = near + dt * (float)k;
        const float xf = axv + bxv * t;
        const float yf = ayv + byv * t;
        const float zf = azv + bzv * t;

        const float x0f = floorf(xf), y0f = floorf(yf), z0f = floorf(zf);
        const float xd = xf - x0f, yd = yf - y0f, zd = zf - z0f;
        const int x0 = (int)x0f, y0 = (int)y0f, z0 = (int)z0f;

        float sr = 0.0f, sg = 0.0f, sb = 0.0f, ss = 0.0f;

        #pragma unroll
        for (int cz = 0; cz < 2; ++cz) {
            const int zi = z0 + cz;
            const bool vz = (zi >= 0) & (zi < VD);
            const int zc = min(max(zi, 0), VD - 1);
            const float wz = cz ? zd : (1.0f - zd);
            #pragma unroll
            for (int cy = 0; cy < 2; ++cy) {
                const int yi = y0 + cy;
                const bool vy = (yi >= 0) & (yi < VD);
                const int yc = min(max(yi, 0), VD - 1);
                const float wy = cy ? yd : (1.0f - yd);
                #pragma unroll
                for (int cxd = 0; cxd < 2; ++cxd) {
                    const int xi = x0 + cxd;
                    const bool vx = (xi >= 0) & (xi < VD);
                    const int xc = min(max(xi, 0), VD - 1);
                    const float wxw = cxd ? xd : (1.0f - xd);
                    const float w = wz * wy * wxw * ((vz & vy & vx) ? 1.0f : 0.0f);
                    const float4 v = *reinterpret_cast<const float4*>(
                        V + (((size_t)(yc * VD + xc)) * VD + (size_t)zc) * 4);
                    sr += w * v.x;
                    sg += w * v.y;
                    sb += w * v.z;
                    ss += w * v.w;
                }
            }
        }

        const float sigma = fmaxf(ss, 0.0f);
        const float dist = (k == NSAMP - 1) ? 1e10f : dt;
        const float alpha = 1.0f - __expf(-sigma * dist);
        const float wgt = alpha * T;
        rr += wgt * sr;
        gg += wgt * sg;
        bb += wgt * sb;
        aw += wgt;
        T *= (1.0f - alpha + 1e-10f);
    }

    // ---- combine 8 segments living on 8 consecutive lanes ----
    // exclusive prefix product of T over the 8-lane group
    float Pfx = 1.0f;
    #pragma unroll
    for (int q = 0; q < SPLIT - 1; ++q) {
        const float tq = __shfl(T, q, SPLIT);
        if (s > q) Pfx *= tq;
    }
    rr *= Pfx; gg *= Pfx; bb *= Pfx; aw *= Pfx;

    // butterfly sum across the 8-lane group
    #pragma unroll
    for (int d = 1; d < SPLIT; d <<= 1) {
        rr += __shfl_xor(rr, d, SPLIT);
        gg += __shfl_xor(gg, d, SPLIT);
        bb += __shfl_xor(bb, d, SPLIT);
        aw += __shfl_xor(aw, d, SPLIT);
    }

    if (s == 0) {
        const float bg = 1.0f - aw;
        float* outb = out + (size_t)b * 3 * N + pix;
        outb[0 * N] = rr + bg;
        outb[1 * N] = gg + bg;
        outb[2 * N] = bb + bg;
    }
}

extern "C" void kernel_launch(void* const* d_in, const int* in_sizes, int n_in,
                              void* d_out, int out_size, void* d_ws, size_t ws_size,
                              hipStream_t stream) {
    const float* rgbsigma = (const float*)d_in[0];
    const float* pose     = (const float*)d_in[1];
    const float* Kmat     = (const float*)d_in[2];
    const float* bmin     = (const float*)d_in[3];
    const float* bmax     = (const float*)d_in[4];
    const int*   dH       = (const int*)d_in[5];
    const int*   dW       = (const int*)d_in[6];
    float* out = (float*)d_out;

    const int rays = out_size / 3;          // B*H*W
    const int totalThreads = rays * SPLIT;
    const int block = 256;
    const int grid = (totalThreads + block - 1) / block;
    VoxelRenderer_kernel<<<grid, block, 0, stream>>>(
        rgbsigma, pose, Kmat, bmin, bmax, dH, dW, out, totalThreads);
}

// Round 5
// 230.386 us; speedup vs baseline: 1.3662x; 1.3662x over previous
//
#include <hip/hip_runtime.h>

#define NSAMP 128
#define VD 128        // voxel grid is 128^3
#define SPLIT 8       // segments per ray == waves per block
#define SEG (NSAMP / SPLIT)
#define RPB 64        // rays per block (= lanes per wave)

__global__ __launch_bounds__(512)
void VoxelRenderer_kernel(const float* __restrict__ vol,   // [B,128,128,128,4]
                          const float* __restrict__ pose,  // [B,4,4]
                          const float* __restrict__ Kmat,  // [B,3,3]
                          const float* __restrict__ bmin,  // [B,3]
                          const float* __restrict__ bmax,  // [B,3]
                          const int* __restrict__ dH,
                          const int* __restrict__ dW,
                          float* __restrict__ out,         // [B,3,H,W]
                          int rays)                        // B*H*W
{
    const int lane = threadIdx.x & 63;        // ray within block
    const int s    = threadIdx.x >> 6;        // segment = wave id
    const int ray  = blockIdx.x * RPB + lane;

    __shared__ float s_rr[SPLIT][RPB];
    __shared__ float s_gg[SPLIT][RPB];
    __shared__ float s_bb[SPLIT][RPB];
    __shared__ float s_aw[SPLIT][RPB];
    __shared__ float s_T [SPLIT][RPB];

    const int H = dH[0], W = dW[0];
    const int N = H * W;

    if (ray < rays) {
        const int b = ray / N;
        const int pix = ray - b * N;
        const int i = pix / W;
        const int j = pix - i * W;

        // ---- camera / ray setup ----
        const float* P  = pose + b * 16;
        const float* Kb = Kmat + b * 9;
        const float fx = Kb[0], cx = Kb[2], fy = Kb[4], cy = Kb[5];

        const float dcx = ((float)j - cx) / fx;
        const float dcy = -((float)i - cy) / fy;
        const float dcz = -1.0f;

        float dx = P[0]*dcx + P[1]*dcy + P[2]*dcz;
        float dy = P[4]*dcx + P[5]*dcy + P[6]*dcz;
        float dz = P[8]*dcx + P[9]*dcy + P[10]*dcz;
        float nrm = sqrtf(dx*dx + dy*dy + dz*dz);
        nrm = fmaxf(nrm, 1e-12f);
        dx /= nrm; dy /= nrm; dz /= nrm;

        const float ox = P[3], oy = P[7], oz = P[11];

        const float bx0 = bmin[b*3+0], by0 = bmin[b*3+1], bz0 = bmin[b*3+2];
        const float bx1 = bmax[b*3+0], by1 = bmax[b*3+1], bz1 = bmax[b*3+2];

        // ---- ray/box intersection (exact reference arithmetic) ----
        const float ivx = 1.0f / (dx + 1e-10f);
        const float ivy = 1.0f / (dy + 1e-10f);
        const float ivz = 1.0f / (dz + 1e-10f);

        float ta, tb;
        ta = (bx0 - ox) * ivx; tb = (bx1 - ox) * ivx;
        const float t1x = fminf(ta, tb), t2x = fmaxf(ta, tb);
        ta = (by0 - oy) * ivy; tb = (by1 - oy) * ivy;
        const float t1y = fminf(ta, tb), t2y = fmaxf(ta, tb);
        ta = (bz0 - oz) * ivz; tb = (bz1 - oz) * ivz;
        const float t1z = fminf(ta, tb), t2z = fmaxf(ta, tb);

        const float near = fmaxf(fmaxf(t1x, fmaxf(t1y, t1z)), 0.1f);
        const float far  = fmaxf(fminf(t2x, fminf(t2y, t2z)), near + 0.1f);

        // ---- voxel-space affine coords: v(t) = a + b*t (align_corners=True) ----
        const float sxs = (bx1 - bx0) + 1e-10f;
        const float sys = (by1 - by0) + 1e-10f;
        const float szs = (bz1 - bz0) + 1e-10f;
        const float C = (float)(VD - 1);
        const float axv = (ox - bx0) / sxs * C, bxv = dx / sxs * C;
        const float ayv = (oy - by0) / sys * C, byv = dy / sys * C;
        const float azv = (oz - bz0) / szs * C, bzv = dz / szs * C;

        const float dt = (far - near) * (1.0f / (float)(NSAMP - 1));

        const float* __restrict__ V = vol + (size_t)b * VD * VD * VD * 4;
        const float4* __restrict__ V4 = reinterpret_cast<const float4*>(V);

        float T = 1.0f;
        float rr = 0.0f, gg = 0.0f, bb = 0.0f, aw = 0.0f;
        const int k0 = s * SEG;

        for (int kk = 0; kk < SEG; ++kk) {
            const int k = k0 + kk;
            const float t = near + dt * (float)k;
            const float xf = axv + bxv * t;
            const float yf = ayv + byv * t;
            const float zf = azv + bzv * t;

            const float x0f = floorf(xf), y0f = floorf(yf), z0f = floorf(zf);
            const float xd = xf - x0f, yd = yf - y0f, zd = zf - z0f;
            const int x0 = (int)x0f, y0 = (int)y0f, z0 = (int)z0f;

            float sr, sg, sb, ss;

            const bool interior = (x0 >= 0) & (x0 < VD-1) & (y0 >= 0) & (y0 < VD-1)
                                & (z0 >= 0) & (z0 < VD-1);
            if (interior) {
                // one base per y-plane; x/z corners via immediate offsets
                const int idx = (y0 * VD + x0) * VD + z0;
                const float4* p0 = V4 + idx;            // y0 plane
                const float4* p1 = p0 + VD * VD;        // y0+1 plane
                const float4 v000 = p0[0];              // [y][x][z]
                const float4 v001 = p0[1];
                const float4 v010 = p0[VD];
                const float4 v011 = p0[VD + 1];
                const float4 v100 = p1[0];
                const float4 v101 = p1[1];
                const float4 v110 = p1[VD];
                const float4 v111 = p1[VD + 1];

                const float xm = 1.0f - xd, ym = 1.0f - yd, zm = 1.0f - zd;
                const float w00 = ym * xm, w01 = ym * xd;
                const float w10 = yd * xm, w11 = yd * xd;
                const float w000 = w00 * zm, w001 = w00 * zd;
                const float w010 = w01 * zm, w011 = w01 * zd;
                const float w100 = w10 * zm, w101 = w10 * zd;
                const float w110 = w11 * zm, w111 = w11 * zd;

                sr = w000*v000.x + w001*v001.x + w010*v010.x + w011*v011.x
                   + w100*v100.x + w101*v101.x + w110*v110.x + w111*v111.x;
                sg = w000*v000.y + w001*v001.y + w010*v010.y + w011*v011.y
                   + w100*v100.y + w101*v101.y + w110*v110.y + w111*v111.y;
                sb = w000*v000.z + w001*v001.z + w010*v010.z + w011*v011.z
                   + w100*v100.z + w101*v101.z + w110*v110.z + w111*v111.z;
                ss = w000*v000.w + w001*v001.w + w010*v010.w + w011*v011.w
                   + w100*v100.w + w101*v101.w + w110*v110.w + w111*v111.w;
            } else {
                sr = 0.0f; sg = 0.0f; sb = 0.0f; ss = 0.0f;
                #pragma unroll
                for (int cz = 0; cz < 2; ++cz) {
                    const int zi = z0 + cz;
                    const bool vz = (zi >= 0) & (zi < VD);
                    const int zc = min(max(zi, 0), VD - 1);
                    const float wz = cz ? zd : (1.0f - zd);
                    #pragma unroll
                    for (int cy = 0; cy < 2; ++cy) {
                        const int yi = y0 + cy;
                        const bool vy = (yi >= 0) & (yi < VD);
                        const int yc = min(max(yi, 0), VD - 1);
                        const float wy = cy ? yd : (1.0f - yd);
                        #pragma unroll
                        for (int cxd = 0; cxd < 2; ++cxd) {
                            const int xi = x0 + cxd;
                            const bool vx = (xi >= 0) & (xi < VD);
                            const int xc = min(max(xi, 0), VD - 1);
                            const float wxw = cxd ? xd : (1.0f - xd);
                            const float w = wz * wy * wxw * ((vz & vy & vx) ? 1.0f : 0.0f);
                            const float4 v = V4[(yc * VD + xc) * VD + zc];
                            sr += w * v.x; sg += w * v.y;
                            sb += w * v.z; ss += w * v.w;
                        }
                    }
                }
            }

            const float sigma = fmaxf(ss, 0.0f);
            const float dist = (k == NSAMP - 1) ? 1e10f : dt;
            const float alpha = 1.0f - __expf(-sigma * dist);
            const float wgt = alpha * T;
            rr += wgt * sr;
            gg += wgt * sg;
            bb += wgt * sb;
            aw += wgt;
            T *= (1.0f - alpha + 1e-10f);
        }

        s_rr[s][lane] = rr;
        s_gg[s][lane] = gg;
        s_bb[s][lane] = bb;
        s_aw[s][lane] = aw;
        s_T [s][lane] = T;
    }

    __syncthreads();

    // ---- epilogue: one lane per ray composes the 8 segments ----
    if (threadIdx.x < RPB && ray < rays) {
        float R = 0.0f, G = 0.0f, Bl = 0.0f, A = 0.0f, Tp = 1.0f;
        #pragma unroll
        for (int q = 0; q < SPLIT; ++q) {
            R  += Tp * s_rr[q][lane];
            G  += Tp * s_gg[q][lane];
            Bl += Tp * s_bb[q][lane];
            A  += Tp * s_aw[q][lane];
            Tp *= s_T[q][lane];
        }
        const int b = ray / N;
        const int pix = ray - b * N;
        const float bg = 1.0f - A;
        float* outb = out + (size_t)b * 3 * N + pix;
        outb[0 * (size_t)N] = R + bg;
        outb[1 * (size_t)N] = G + bg;
        outb[2 * (size_t)N] = Bl + bg;
    }
}

extern "C" void kernel_launch(void* const* d_in, const int* in_sizes, int n_in,
                              void* d_out, int out_size, void* d_ws, size_t ws_size,
                              hipStream_t stream) {
    const float* rgbsigma = (const float*)d_in[0];
    const float* pose     = (const float*)d_in[1];
    const float* Kmat     = (const float*)d_in[2];
    const float* bmin     = (const float*)d_in[3];
    const float* bmax     = (const float*)d_in[4];
    const int*   dH       = (const int*)d_in[5];
    const int*   dW       = (const int*)d_in[6];
    float* out = (float*)d_out;

    const int rays = out_size / 3;              // B*H*W
    const int grid = (rays + RPB - 1) / RPB;    // 64 rays per block
    VoxelRenderer_kernel<<<grid, 512, 0, stream>>>(
        rgbsigma, pose, Kmat, bmin, bmax, dH, dW, out, rays);
}

// Round 7
// 138.855 us; speedup vs baseline: 2.2668x; 1.6592x over previous
//
#include <hip/hip_runtime.h>

#define NSAMP 128
#define VD 128   // voxel grid is 128^3

struct Corner8 {
    float4 v0, v1, v2, v3, v4, v5, v6, v7;
    float  w0, w1, w2, w3, w4, w5, w6, w7;
};

// Branch-free trilinear tap: clamp coords, validity = clamp-identity,
// validity folded into per-axis weights. Issues 8 independent dwordx4 loads.
__device__ __forceinline__ void fetch_sample(
    Corner8& Bf, const float4* __restrict__ V4, float t,
    float axv, float bxv, float ayv, float byv, float azv, float bzv)
{
    const float xf = axv + bxv * t;
    const float yf = ayv + byv * t;
    const float zf = azv + bzv * t;
    const float x0f = floorf(xf), y0f = floorf(yf), z0f = floorf(zf);
    const float xd = xf - x0f, yd = yf - y0f, zd = zf - z0f;
    const int x0 = (int)x0f, y0 = (int)y0f, z0 = (int)z0f;
    const int x1 = x0 + 1, y1 = y0 + 1, z1 = z0 + 1;

    const int xc0 = min(max(x0, 0), VD - 1), xc1 = min(max(x1, 0), VD - 1);
    const int yc0 = min(max(y0, 0), VD - 1), yc1 = min(max(y1, 0), VD - 1);
    const int zc0 = min(max(z0, 0), VD - 1), zc1 = min(max(z1, 0), VD - 1);

    // valid iff clamp was identity (coord in [0,127])
    const float vx0 = (x0 == xc0) ? 1.0f : 0.0f;
    const float vx1 = (x1 == xc1) ? 1.0f : 0.0f;
    const float vy0 = (y0 == yc0) ? 1.0f : 0.0f;
    const float vy1 = (y1 == yc1) ? 1.0f : 0.0f;
    const float vz0 = (z0 == zc0) ? 1.0f : 0.0f;
    const float vz1 = (z1 == zc1) ? 1.0f : 0.0f;

    const float wx0 = (1.0f - xd) * vx0, wx1 = xd * vx1;
    const float wy0 = (1.0f - yd) * vy0, wy1 = yd * vy1;
    const float wz0 = (1.0f - zd) * vz0, wz1 = zd * vz1;

    // memory layout (float4 units): idx = (y*128 + x)*128 + z
    const int r0 = yc0 << 14, r1 = yc1 << 14;
    const int c0 = xc0 << 7,  c1 = xc1 << 7;
    const int i00 = r0 + c0, i01 = r0 + c1;
    const int i10 = r1 + c0, i11 = r1 + c1;

    Bf.v0 = V4[i00 + zc0];
    Bf.v1 = V4[i00 + zc1];
    Bf.v2 = V4[i01 + zc0];
    Bf.v3 = V4[i01 + zc1];
    Bf.v4 = V4[i10 + zc0];
    Bf.v5 = V4[i10 + zc1];
    Bf.v6 = V4[i11 + zc0];
    Bf.v7 = V4[i11 + zc1];

    Bf.w0 = wy0 * wx0 * wz0;
    Bf.w1 = wy0 * wx0 * wz1;
    Bf.w2 = wy0 * wx1 * wz0;
    Bf.w3 = wy0 * wx1 * wz1;
    Bf.w4 = wy1 * wx0 * wz0;
    Bf.w5 = wy1 * wx0 * wz1;
    Bf.w6 = wy1 * wx1 * wz0;
    Bf.w7 = wy1 * wx1 * wz1;
}

__device__ __forceinline__ void consume_sample(
    const Corner8& Bf, bool last, float dt,
    float& T, float& rr, float& gg, float& bb, float& aw)
{
    const float sr = Bf.w0*Bf.v0.x + Bf.w1*Bf.v1.x + Bf.w2*Bf.v2.x + Bf.w3*Bf.v3.x
                   + Bf.w4*Bf.v4.x + Bf.w5*Bf.v5.x + Bf.w6*Bf.v6.x + Bf.w7*Bf.v7.x;
    const float sg = Bf.w0*Bf.v0.y + Bf.w1*Bf.v1.y + Bf.w2*Bf.v2.y + Bf.w3*Bf.v3.y
                   + Bf.w4*Bf.v4.y + Bf.w5*Bf.v5.y + Bf.w6*Bf.v6.y + Bf.w7*Bf.v7.y;
    const float sb = Bf.w0*Bf.v0.z + Bf.w1*Bf.v1.z + Bf.w2*Bf.v2.z + Bf.w3*Bf.v3.z
                   + Bf.w4*Bf.v4.z + Bf.w5*Bf.v5.z + Bf.w6*Bf.v6.z + Bf.w7*Bf.v7.z;
    const float ss = Bf.w0*Bf.v0.w + Bf.w1*Bf.v1.w + Bf.w2*Bf.v2.w + Bf.w3*Bf.v3.w
                   + Bf.w4*Bf.v4.w + Bf.w5*Bf.v5.w + Bf.w6*Bf.v6.w + Bf.w7*Bf.v7.w;

    const float sigma = fmaxf(ss, 0.0f);
    const float dist  = last ? 1e10f : dt;
    const float alpha = 1.0f - __expf(-sigma * dist);
    const float wgt   = alpha * T;
    rr += wgt * sr;
    gg += wgt * sg;
    bb += wgt * sb;
    aw += wgt;
    T *= (1.0f - alpha + 1e-10f);
}

__global__ __launch_bounds__(256, 1)
void VoxelRenderer_kernel(const float* __restrict__ vol,   // [B,128,128,128,4]
                          const float* __restrict__ pose,  // [B,4,4]
                          const float* __restrict__ Kmat,  // [B,3,3]
                          const float* __restrict__ bmin,  // [B,3]
                          const float* __restrict__ bmax,  // [B,3]
                          const int* __restrict__ dH,
                          const int* __restrict__ dW,
                          float* __restrict__ out,         // [B,3,H,W]
                          int total)                       // B*H*W
{
    const int tid = blockIdx.x * blockDim.x + threadIdx.x;
    if (tid >= total) return;
    const int H = dH[0], W = dW[0];
    const int N = H * W;
    const int b = tid / N;
    const int pix = tid - b * N;
    const int i = pix / W;
    const int j = pix - i * W;

    // ---- camera / ray setup ----
    const float* P  = pose + b * 16;
    const float* Kb = Kmat + b * 9;
    const float fx = Kb[0], cx = Kb[2], fy = Kb[4], cy = Kb[5];

    const float dcx = ((float)j - cx) / fx;
    const float dcy = -((float)i - cy) / fy;
    const float dcz = -1.0f;

    float dx = P[0]*dcx + P[1]*dcy + P[2]*dcz;
    float dy = P[4]*dcx + P[5]*dcy + P[6]*dcz;
    float dz = P[8]*dcx + P[9]*dcy + P[10]*dcz;
    float nrm = sqrtf(dx*dx + dy*dy + dz*dz);
    nrm = fmaxf(nrm, 1e-12f);
    dx /= nrm; dy /= nrm; dz /= nrm;

    const float ox = P[3], oy = P[7], oz = P[11];

    const float bx0 = bmin[b*3+0], by0 = bmin[b*3+1], bz0 = bmin[b*3+2];
    const float bx1 = bmax[b*3+0], by1 = bmax[b*3+1], bz1 = bmax[b*3+2];

    // ---- ray/box intersection (exact reference arithmetic) ----
    const float ivx = 1.0f / (dx + 1e-10f);
    const float ivy = 1.0f / (dy + 1e-10f);
    const float ivz = 1.0f / (dz + 1e-10f);

    float ta, tb;
    ta = (bx0 - ox) * ivx; tb = (bx1 - ox) * ivx;
    const float t1x = fminf(ta, tb), t2x = fmaxf(ta, tb);
    ta = (by0 - oy) * ivy; tb = (by1 - oy) * ivy;
    const float t1y = fminf(ta, tb), t2y = fmaxf(ta, tb);
    ta = (bz0 - oz) * ivz; tb = (bz1 - oz) * ivz;
    const float t1z = fminf(ta, tb), t2z = fmaxf(ta, tb);

    const float near = fmaxf(fmaxf(t1x, fmaxf(t1y, t1z)), 0.1f);
    const float far  = fmaxf(fminf(t2x, fminf(t2y, t2z)), near + 0.1f);

    // ---- voxel-space affine coords: v(t) = a + b*t (align_corners=True) ----
    const float sxs = (bx1 - bx0) + 1e-10f;
    const float sys = (by1 - by0) + 1e-10f;
    const float szs = (bz1 - bz0) + 1e-10f;
    const float C = (float)(VD - 1);
    const float axv = (ox - bx0) / sxs * C, bxv = dx / sxs * C;
    const float ayv = (oy - by0) / sys * C, byv = dy / sys * C;
    const float azv = (oz - bz0) / szs * C, bzv = dz / szs * C;

    const float dt = (far - near) * (1.0f / (float)(NSAMP - 1));

    const float4* __restrict__ V4 =
        reinterpret_cast<const float4*>(vol + (size_t)b * VD * VD * VD * 4);

    float T = 1.0f;
    float rr = 0.0f, gg = 0.0f, bb = 0.0f, aw = 0.0f;

    // ---- depth-2 software-pipelined sample loop ----
    Corner8 A, Bf;
    fetch_sample(A, V4, near, axv, bxv, ayv, byv, azv, bzv);

    for (int k = 0; k < NSAMP; k += 2) {
        fetch_sample(Bf, V4, near + dt * (float)(k + 1),
                     axv, bxv, ayv, byv, azv, bzv);
        consume_sample(A, false, dt, T, rr, gg, bb, aw);   // k even, never last
        if (k + 2 < NSAMP)
            fetch_sample(A, V4, near + dt * (float)(k + 2),
                         axv, bxv, ayv, byv, azv, bzv);
        consume_sample(Bf, (k + 1) == (NSAMP - 1), dt, T, rr, gg, bb, aw);
    }

    const float bg = 1.0f - aw;
    float* outb = out + (size_t)b * 3 * N + pix;
    outb[0 * (size_t)N] = rr + bg;
    outb[1 * (size_t)N] = gg + bg;
    outb[2 * (size_t)N] = bb + bg;
}

extern "C" void kernel_launch(void* const* d_in, const int* in_sizes, int n_in,
                              void* d_out, int out_size, void* d_ws, size_t ws_size,
                              hipStream_t stream) {
    const float* rgbsigma = (const float*)d_in[0];
    const float* pose     = (const float*)d_in[1];
    const float* Kmat     = (const float*)d_in[2];
    const float* bmin     = (const float*)d_in[3];
    const float* bmax     = (const float*)d_in[4];
    const int*   dH       = (const int*)d_in[5];
    const int*   dW       = (const int*)d_in[6];
    float* out = (float*)d_out;

    const int total = out_size / 3;  // B*H*W rays
    const int block = 256;
    const int grid = (total + block - 1) / block;
    VoxelRenderer_kernel<<<grid, block, 0, stream>>>(
        rgbsigma, pose, Kmat, bmin, bmax, dH, dW, out, total);
}